// Round 1
// baseline (173.257 us; speedup 1.0000x reference)
//
#include <hip/hip_runtime.h>

// Guided filter, r=5 (11x11 box), B=8 C=3 H=W=512, fp32.
// Zero-padded box conv divided by N=box(ones)  ==  sum over valid window / count,
// and count(i,j) = cnt(i)*cnt(j) is separable -> computed analytically.
//
// Kernel A: x,y -> A,b   (box of x,y,xy,xx; A=cov/(var+eps); b=my-A*mx)
// Kernel B: A,b,x -> out (box of A,b; out = meanA*x + meanb)

#define R    5
#define KS   11
#define TX   64
#define TY   16
#define HLO  (TY + 2 * R)   // 26 rows incl. halo
#define WLO  (TX + 2 * R)   // 74 cols incl. halo
#define WPAD (WLO + 2)      // 76, LDS row padding

#define IMG_H 512
#define IMG_W 512

__device__ __forceinline__ int clampcnt(int g, int n) {
    int lo = max(g - R, 0);
    int hi = min(g + R, n - 1);
    return hi - lo + 1;
}

__global__ __launch_bounds__(256) void guided_stage_a(
        const float* __restrict__ x, const float* __restrict__ y,
        float2* __restrict__ ab) {
    __shared__ float xs[HLO][WPAD];
    __shared__ float ys[HLO][WPAD];
    __shared__ float4 h4[HLO][TX];

    const int plane = blockIdx.z;
    const int tx0 = blockIdx.x * TX;
    const int ty0 = blockIdx.y * TY;
    const int tid = threadIdx.x;
    const size_t pbase = (size_t)plane * IMG_H * IMG_W;
    const float* xp = x + pbase;
    const float* yp = y + pbase;

    // ---- load x,y tile + halo (zeros outside image = conv zero padding) ----
    for (int idx = tid; idx < HLO * WLO; idx += 256) {
        int rr = idx / WLO, cc = idx % WLO;
        int gy = ty0 + rr - R, gx = tx0 + cc - R;
        float xv = 0.f, yv = 0.f;
        if (gy >= 0 && gy < IMG_H && gx >= 0 && gx < IMG_W) {
            xv = xp[gy * IMG_W + gx];
            yv = yp[gy * IMG_W + gx];
        }
        xs[rr][cc] = xv;
        ys[rr][cc] = yv;
    }
    __syncthreads();

    // ---- horizontal 11-tap sums of (x, y, xy, xx) ----
    for (int idx = tid; idx < HLO * TX; idx += 256) {
        int rr = idx / TX, cc = idx % TX;
        float sx = 0.f, sy = 0.f, sxy = 0.f, sxx = 0.f;
#pragma unroll
        for (int d = 0; d < KS; ++d) {
            float xv = xs[rr][cc + d];
            float yv = ys[rr][cc + d];
            sx  += xv;
            sy  += yv;
            sxy += xv * yv;
            sxx += xv * xv;
        }
        h4[rr][cc] = make_float4(sx, sy, sxy, sxx);
    }
    __syncthreads();

    // ---- vertical 11-tap sums + A,b ----
    for (int idx = tid; idx < TY * TX; idx += 256) {
        int oy = idx / TX, ox = idx % TX;
        float sx = 0.f, sy = 0.f, sxy = 0.f, sxx = 0.f;
#pragma unroll
        for (int d = 0; d < KS; ++d) {
            float4 v = h4[oy + d][ox];
            sx  += v.x;
            sy  += v.y;
            sxy += v.z;
            sxx += v.w;
        }
        int gy = ty0 + oy, gx = tx0 + ox;
        float inv = 1.0f / (float)(clampcnt(gy, IMG_H) * clampcnt(gx, IMG_W));
        float mx = sx * inv, my = sy * inv;
        float cov = sxy * inv - mx * my;
        float var = sxx * inv - mx * mx;
        float A = cov / (var + 0.01f);
        float b = my - A * mx;
        ab[pbase + (size_t)gy * IMG_W + gx] = make_float2(A, b);
    }
}

__global__ __launch_bounds__(256) void guided_stage_b(
        const float2* __restrict__ ab, const float* __restrict__ x,
        float* __restrict__ out) {
    __shared__ float2 abt[HLO][WPAD];
    __shared__ float2 h2[HLO][TX];

    const int plane = blockIdx.z;
    const int tx0 = blockIdx.x * TX;
    const int ty0 = blockIdx.y * TY;
    const int tid = threadIdx.x;
    const size_t pbase = (size_t)plane * IMG_H * IMG_W;
    const float2* abp = ab + pbase;
    const float* xp = x + pbase;

    // ---- load A,b tile + halo ----
    for (int idx = tid; idx < HLO * WLO; idx += 256) {
        int rr = idx / WLO, cc = idx % WLO;
        int gy = ty0 + rr - R, gx = tx0 + cc - R;
        float2 v = make_float2(0.f, 0.f);
        if (gy >= 0 && gy < IMG_H && gx >= 0 && gx < IMG_W) {
            v = abp[gy * IMG_W + gx];
        }
        abt[rr][cc] = v;
    }
    __syncthreads();

    // ---- horizontal 11-tap sums of (A, b) ----
    for (int idx = tid; idx < HLO * TX; idx += 256) {
        int rr = idx / TX, cc = idx % TX;
        float sa = 0.f, sb = 0.f;
#pragma unroll
        for (int d = 0; d < KS; ++d) {
            float2 v = abt[rr][cc + d];
            sa += v.x;
            sb += v.y;
        }
        h2[rr][cc] = make_float2(sa, sb);
    }
    __syncthreads();

    // ---- vertical 11-tap sums + output ----
    for (int idx = tid; idx < TY * TX; idx += 256) {
        int oy = idx / TX, ox = idx % TX;
        float sa = 0.f, sb = 0.f;
#pragma unroll
        for (int d = 0; d < KS; ++d) {
            float2 v = h2[oy + d][ox];
            sa += v.x;
            sb += v.y;
        }
        int gy = ty0 + oy, gx = tx0 + ox;
        float inv = 1.0f / (float)(clampcnt(gy, IMG_H) * clampcnt(gx, IMG_W));
        float mA = sa * inv;
        float mB = sb * inv;
        out[pbase + (size_t)gy * IMG_W + gx] = mA * xp[gy * IMG_W + gx] + mB;
    }
}

extern "C" void kernel_launch(void* const* d_in, const int* in_sizes, int n_in,
                              void* d_out, int out_size, void* d_ws, size_t ws_size,
                              hipStream_t stream) {
    const float* x = (const float*)d_in[0];
    const float* y = (const float*)d_in[1];
    // d_in[2] is r (==5), compile-time constant R here.
    float* out = (float*)d_out;
    float2* ab = (float2*)d_ws;  // planes*H*W float2 = ~50 MB

    const int planes = in_sizes[0] / (IMG_H * IMG_W);  // 24

    dim3 grid(IMG_W / TX, IMG_H / TY, planes);
    guided_stage_a<<<grid, 256, 0, stream>>>(x, y, ab);
    guided_stage_b<<<grid, 256, 0, stream>>>(ab, x, out);
}

// Round 3
// 159.827 us; speedup vs baseline: 1.0840x; 1.0840x over previous
//
#include <hip/hip_runtime.h>

// Guided filter r=5, B=8 C=3 H=W=512 fp32, two kernels:
//   A: x,y -> (A,b)  via box(x,y,xy,xx)
//   B: (A,b),x -> out via box(A,b)
// Box = vertical 11-sum (sliding window, coalesced global loads, lane=column)
//       -> LDS -> horizontal 11-sum (sliding window over float4/float2 LDS).
// Zero-pad conv / N == valid-window sum * 1/(cnt_y*cnt_x), counts analytic.
// VPAD=75 (odd): all LDS wave access patterns hit the words/bank floor.

#define R    5
#define KS   11
#define TX   64
#define TY   16
#define WLO  (TX + 2 * R)   // 74 columns incl. halo
#define VPAD 75
#define IMG  512

__device__ __forceinline__ int clampcnt(int g) {
    int lo = max(g - R, 0);
    int hi = min(g + R, IMG - 1);
    return hi - lo + 1;
}

__global__ __launch_bounds__(256) void guided_stage_a(
        const float* __restrict__ x, const float* __restrict__ y,
        float2* __restrict__ ab) {
    __shared__ float4 v4[TY][VPAD];

    const int plane = blockIdx.z;
    const int tx0 = blockIdx.x * TX;
    const int ty0 = blockIdx.y * TY;
    const int tid = threadIdx.x;
    const size_t pbase = (size_t)plane * IMG * IMG;
    const float* xp = x + pbase;
    const float* yp = y + pbase;

    // ---- Phase 1: vertical 11-sums of (x,y,xy,xx), sliding down.
    // 74 columns x 2 row-segments (8 rows each) = 148 active threads.
    if (tid < 2 * WLO) {
        const int seg = (tid >= WLO) ? 1 : 0;
        const int cc  = tid - seg * WLO;
        const int r0  = seg * 8;
        const int gx  = tx0 + cc - R;
        const bool xok = (gx >= 0 && gx < IMG);

        float sx = 0.f, sy = 0.f, sxy = 0.f, sxx = 0.f;
#pragma unroll
        for (int j = 0; j < KS; ++j) {
            int gy = ty0 + r0 - R + j;
            if (xok && gy >= 0 && gy < IMG) {
                size_t o = (size_t)gy * IMG + gx;
                float xv = xp[o], yv = yp[o];
                sx += xv; sy += yv; sxy += xv * yv; sxx += xv * xv;
            }
        }
        v4[r0][cc] = make_float4(sx, sy, sxy, sxx);
#pragma unroll
        for (int s = 1; s < 8; ++s) {
            int gyn = ty0 + r0 + s + R;
            int gyo = ty0 + r0 + s - R - 1;
            if (xok && gyn >= 0 && gyn < IMG) {
                size_t o = (size_t)gyn * IMG + gx;
                float xn = xp[o], yn = yp[o];
                sx += xn; sy += yn; sxy += xn * yn; sxx += xn * xn;
            }
            if (xok && gyo >= 0 && gyo < IMG) {
                size_t o = (size_t)gyo * IMG + gx;
                float xo = xp[o], yo = yp[o];
                sx -= xo; sy -= yo; sxy -= xo * yo; sxx -= xo * xo;
            }
            v4[r0 + s][cc] = make_float4(sx, sy, sxy, sxx);
        }
    }
    __syncthreads();

    // ---- Phase 2: horizontal 11-sums, sliding. 16 rows x 16 chunks of 4 cols.
    {
        const int oy = tid >> 4;   // 0..15
        const int ch = tid & 15;   // 0..15
        const int c0 = ch * 4;
        const int gy = ty0 + oy;
        const float cy = (float)clampcnt(gy);

        float sx = 0.f, sy = 0.f, sxy = 0.f, sxx = 0.f;
#pragma unroll
        for (int d = 0; d < KS; ++d) {
            float4 v = v4[oy][c0 + d];
            sx += v.x; sy += v.y; sxy += v.z; sxx += v.w;
        }
        float2 res[4];
#pragma unroll
        for (int i = 0; i < 4; ++i) {
            const int ox = c0 + i;
            if (i > 0) {
                float4 a = v4[oy][ox + 10];
                float4 b = v4[oy][ox - 1];
                sx += a.x - b.x; sy += a.y - b.y;
                sxy += a.z - b.z; sxx += a.w - b.w;
            }
            float inv = 1.0f / (cy * (float)clampcnt(tx0 + ox));
            float mx = sx * inv, my = sy * inv;
            float cov = sxy * inv - mx * my;
            float var = sxx * inv - mx * mx;
            float A = cov / (var + 0.01f);
            res[i] = make_float2(A, my - A * mx);
        }
        // 4 consecutive float2 = 32 B, 16B-aligned (c0 multiple of 4) -> 2x dwordx4
        float4* dst = reinterpret_cast<float4*>(&ab[pbase + (size_t)gy * IMG + tx0 + c0]);
        dst[0] = make_float4(res[0].x, res[0].y, res[1].x, res[1].y);
        dst[1] = make_float4(res[2].x, res[2].y, res[3].x, res[3].y);
    }
}

__global__ __launch_bounds__(256) void guided_stage_b(
        const float2* __restrict__ ab, const float* __restrict__ x,
        float* __restrict__ out) {
    __shared__ float2 v2[TY][VPAD];

    const int plane = blockIdx.z;
    const int tx0 = blockIdx.x * TX;
    const int ty0 = blockIdx.y * TY;
    const int tid = threadIdx.x;
    const size_t pbase = (size_t)plane * IMG * IMG;
    const float2* abp = ab + pbase;
    const float* xp = x + pbase;

    // ---- Phase 1: vertical 11-sums of (A,b), sliding down.
    if (tid < 2 * WLO) {
        const int seg = (tid >= WLO) ? 1 : 0;
        const int cc  = tid - seg * WLO;
        const int r0  = seg * 8;
        const int gx  = tx0 + cc - R;
        const bool xok = (gx >= 0 && gx < IMG);

        float sa = 0.f, sb = 0.f;
#pragma unroll
        for (int j = 0; j < KS; ++j) {
            int gy = ty0 + r0 - R + j;
            if (xok && gy >= 0 && gy < IMG) {
                float2 v = abp[(size_t)gy * IMG + gx];
                sa += v.x; sb += v.y;
            }
        }
        v2[r0][cc] = make_float2(sa, sb);
#pragma unroll
        for (int s = 1; s < 8; ++s) {
            int gyn = ty0 + r0 + s + R;
            int gyo = ty0 + r0 + s - R - 1;
            if (xok && gyn >= 0 && gyn < IMG) {
                float2 v = abp[(size_t)gyn * IMG + gx];
                sa += v.x; sb += v.y;
            }
            if (xok && gyo >= 0 && gyo < IMG) {
                float2 v = abp[(size_t)gyo * IMG + gx];
                sa -= v.x; sb -= v.y;
            }
            v2[r0 + s][cc] = make_float2(sa, sb);
        }
    }
    __syncthreads();

    // ---- Phase 2: horizontal 11-sums, sliding; out = meanA*x + meanb.
    {
        const int oy = tid >> 4;
        const int ch = tid & 15;
        const int c0 = ch * 4;
        const int gy = ty0 + oy;
        const float cy = (float)clampcnt(gy);

        float sa = 0.f, sb = 0.f;
#pragma unroll
        for (int d = 0; d < KS; ++d) {
            float2 v = v2[oy][c0 + d];
            sa += v.x; sb += v.y;
        }
        const size_t obase = (size_t)gy * IMG + tx0 + c0;
        const float4 xv4 = *reinterpret_cast<const float4*>(&xp[obase]);
        const float xv[4] = {xv4.x, xv4.y, xv4.z, xv4.w};
        float res[4];
#pragma unroll
        for (int i = 0; i < 4; ++i) {
            const int ox = c0 + i;
            if (i > 0) {
                float2 a = v2[oy][ox + 10];
                float2 b = v2[oy][ox - 1];
                sa += a.x - b.x; sb += a.y - b.y;
            }
            float inv = 1.0f / (cy * (float)clampcnt(tx0 + ox));
            res[i] = (sa * inv) * xv[i] + (sb * inv);
        }
        *reinterpret_cast<float4*>(&out[pbase + obase]) =
            make_float4(res[0], res[1], res[2], res[3]);
    }
}

extern "C" void kernel_launch(void* const* d_in, const int* in_sizes, int n_in,
                              void* d_out, int out_size, void* d_ws, size_t ws_size,
                              hipStream_t stream) {
    const float* x = (const float*)d_in[0];
    const float* y = (const float*)d_in[1];
    float* out = (float*)d_out;
    float2* ab = (float2*)d_ws;  // planes*H*W float2 ~ 50 MB

    const int planes = in_sizes[0] / (IMG * IMG);  // 24

    dim3 grid(IMG / TX, IMG / TY, planes);
    guided_stage_a<<<grid, 256, 0, stream>>>(x, y, ab);
    guided_stage_b<<<grid, 256, 0, stream>>>(ab, x, out);
}

// Round 4
// 125.934 us; speedup vs baseline: 1.3758x; 1.2691x over previous
//
#include <hip/hip_runtime.h>

// Guided filter r=5, B=8 C=3 H=W=512 fp32, two kernels:
//   A: x,y -> (A,b)  via box(x,y,xy,xx)
//   B: (A,b),x -> out via box(A,b)
// Box = vertical 11-sum (register-array sliding window, coalesced global loads)
//       -> LDS (gap-swizzled) -> horizontal 11-sum (sliding window).
// Zero-pad conv / N == valid-window sum * 1/(cnt_y*cnt_x), counts analytic.
// LDS gap swizzle P(c)=c+c/4 breaks the 16-words-per-lane stride that caused
// 8-way bank conflicts (3.3M conflict cycles in round 3).

#define R    5
#define KS   11
#define TX   64
#define TY   16
#define WLO  (TX + 2 * R)     // 74 columns incl. halo
#define PCOLS 94              // P(91)=.. max P(73)=91, round up
#define IMG  512

#define P(c) ((c) + ((c) >> 2))

__device__ __forceinline__ int clampcnt(int g) {
    int lo = max(g - R, 0);
    int hi = min(g + R, IMG - 1);
    return hi - lo + 1;
}

__global__ __launch_bounds__(256) void guided_stage_a(
        const float* __restrict__ x, const float* __restrict__ y,
        float2* __restrict__ ab) {
    __shared__ float4 v4[TY][PCOLS];

    const int plane = blockIdx.z;
    const int tx0 = blockIdx.x * TX;
    const int ty0 = blockIdx.y * TY;
    const int tid = threadIdx.x;
    const size_t pbase = (size_t)plane * IMG * IMG;
    const float* xp = x + pbase;
    const float* yp = y + pbase;
    const bool interior = (blockIdx.x > 0) & (blockIdx.x < gridDim.x - 1) &
                          (blockIdx.y > 0) & (blockIdx.y < gridDim.y - 1);

    // ---- Phase 1: vertical 11-sums of (x,y,xy,xx).
    // 74 cols x 2 segments of 8 output rows. Each thread loads its 18-row
    // column into registers (independent loads -> all in flight), then forms
    // the 8 window sums purely from registers.
    if (tid < 2 * WLO) {
        const int seg = (tid >= WLO) ? 1 : 0;
        const int cc  = tid - seg * WLO;
        const int r0  = seg * 8;
        const int gx  = tx0 + cc - R;
        const int gy0 = ty0 + r0 - R;

        float xv[18], yv[18];
        if (interior) {
#pragma unroll
            for (int j = 0; j < 18; ++j) {
                size_t o = (size_t)(gy0 + j) * IMG + gx;
                xv[j] = xp[o];
                yv[j] = yp[o];
            }
        } else {
            const bool xok = (gx >= 0 && gx < IMG);
#pragma unroll
            for (int j = 0; j < 18; ++j) {
                int gy = gy0 + j;
                bool ok = xok && ((unsigned)gy < (unsigned)IMG);
                size_t o = (size_t)gy * IMG + gx;
                xv[j] = ok ? xp[o] : 0.f;
                yv[j] = ok ? yp[o] : 0.f;
            }
        }

        float sx = 0.f, sy = 0.f, sxy = 0.f, sxx = 0.f;
#pragma unroll
        for (int j = 0; j < KS; ++j) {
            sx += xv[j]; sy += yv[j];
            sxy += xv[j] * yv[j]; sxx += xv[j] * xv[j];
        }
        v4[r0][P(cc)] = make_float4(sx, sy, sxy, sxx);
#pragma unroll
        for (int s = 1; s < 8; ++s) {
            float xn = xv[s + 10], yn = yv[s + 10];
            float xo = xv[s - 1],  yo = yv[s - 1];
            sx  += xn - xo;
            sy  += yn - yo;
            sxy += xn * yn - xo * yo;
            sxx += xn * xn - xo * xo;
            v4[r0 + s][P(cc)] = make_float4(sx, sy, sxy, sxx);
        }
    }
    __syncthreads();

    // ---- Phase 2: horizontal 11-sums, sliding. 16 rows x 16 chunks of 4 cols.
    {
        const int oy = tid >> 4;   // 0..15
        const int ch = tid & 15;   // 0..15
        const int c0 = ch * 4;
        const int gy = ty0 + oy;

        float sx = 0.f, sy = 0.f, sxy = 0.f, sxx = 0.f;
#pragma unroll
        for (int d = 0; d < KS; ++d) {
            float4 v = v4[oy][P(c0 + d)];
            sx += v.x; sy += v.y; sxy += v.z; sxx += v.w;
        }
        const float cy = (float)clampcnt(gy);
        float2 res[4];
#pragma unroll
        for (int i = 0; i < 4; ++i) {
            const int ox = c0 + i;
            if (i > 0) {
                float4 a = v4[oy][P(ox + 10)];
                float4 b = v4[oy][P(ox - 1)];
                sx += a.x - b.x; sy += a.y - b.y;
                sxy += a.z - b.z; sxx += a.w - b.w;
            }
            float inv = interior ? (1.0f / 121.0f)
                                 : 1.0f / (cy * (float)clampcnt(tx0 + ox));
            float mx = sx * inv, my = sy * inv;
            float cov = sxy * inv - mx * my;
            float var = sxx * inv - mx * mx;
            float A = cov / (var + 0.01f);
            res[i] = make_float2(A, my - A * mx);
        }
        float4* dst = reinterpret_cast<float4*>(&ab[pbase + (size_t)gy * IMG + tx0 + c0]);
        dst[0] = make_float4(res[0].x, res[0].y, res[1].x, res[1].y);
        dst[1] = make_float4(res[2].x, res[2].y, res[3].x, res[3].y);
    }
}

__global__ __launch_bounds__(256) void guided_stage_b(
        const float2* __restrict__ ab, const float* __restrict__ x,
        float* __restrict__ out) {
    __shared__ float2 v2[TY][PCOLS];

    const int plane = blockIdx.z;
    const int tx0 = blockIdx.x * TX;
    const int ty0 = blockIdx.y * TY;
    const int tid = threadIdx.x;
    const size_t pbase = (size_t)plane * IMG * IMG;
    const float2* abp = ab + pbase;
    const float* xp = x + pbase;
    const bool interior = (blockIdx.x > 0) & (blockIdx.x < gridDim.x - 1) &
                          (blockIdx.y > 0) & (blockIdx.y < gridDim.y - 1);

    // ---- Phase 1: vertical 11-sums of (A,b) via register-array window.
    if (tid < 2 * WLO) {
        const int seg = (tid >= WLO) ? 1 : 0;
        const int cc  = tid - seg * WLO;
        const int r0  = seg * 8;
        const int gx  = tx0 + cc - R;
        const int gy0 = ty0 + r0 - R;

        float2 av[18];
        if (interior) {
#pragma unroll
            for (int j = 0; j < 18; ++j) {
                av[j] = abp[(size_t)(gy0 + j) * IMG + gx];
            }
        } else {
            const bool xok = (gx >= 0 && gx < IMG);
#pragma unroll
            for (int j = 0; j < 18; ++j) {
                int gy = gy0 + j;
                bool ok = xok && ((unsigned)gy < (unsigned)IMG);
                size_t o = (size_t)gy * IMG + gx;
                av[j] = ok ? abp[o] : make_float2(0.f, 0.f);
            }
        }

        float sa = 0.f, sb = 0.f;
#pragma unroll
        for (int j = 0; j < KS; ++j) { sa += av[j].x; sb += av[j].y; }
        v2[r0][P(cc)] = make_float2(sa, sb);
#pragma unroll
        for (int s = 1; s < 8; ++s) {
            sa += av[s + 10].x - av[s - 1].x;
            sb += av[s + 10].y - av[s - 1].y;
            v2[r0 + s][P(cc)] = make_float2(sa, sb);
        }
    }
    __syncthreads();

    // ---- Phase 2: horizontal 11-sums, sliding; out = meanA*x + meanb.
    {
        const int oy = tid >> 4;
        const int ch = tid & 15;
        const int c0 = ch * 4;
        const int gy = ty0 + oy;

        float sa = 0.f, sb = 0.f;
#pragma unroll
        for (int d = 0; d < KS; ++d) {
            float2 v = v2[oy][P(c0 + d)];
            sa += v.x; sb += v.y;
        }
        const float cy = (float)clampcnt(gy);
        const size_t obase = (size_t)gy * IMG + tx0 + c0;
        const float4 xv4 = *reinterpret_cast<const float4*>(&xp[obase]);
        const float xv[4] = {xv4.x, xv4.y, xv4.z, xv4.w};
        float res[4];
#pragma unroll
        for (int i = 0; i < 4; ++i) {
            const int ox = c0 + i;
            if (i > 0) {
                float2 a = v2[oy][P(ox + 10)];
                float2 b = v2[oy][P(ox - 1)];
                sa += a.x - b.x; sb += a.y - b.y;
            }
            float inv = interior ? (1.0f / 121.0f)
                                 : 1.0f / (cy * (float)clampcnt(tx0 + ox));
            res[i] = (sa * inv) * xv[i] + (sb * inv);
        }
        *reinterpret_cast<float4*>(&out[pbase + obase]) =
            make_float4(res[0], res[1], res[2], res[3]);
    }
}

extern "C" void kernel_launch(void* const* d_in, const int* in_sizes, int n_in,
                              void* d_out, int out_size, void* d_ws, size_t ws_size,
                              hipStream_t stream) {
    const float* x = (const float*)d_in[0];
    const float* y = (const float*)d_in[1];
    float* out = (float*)d_out;
    float2* ab = (float2*)d_ws;  // planes*H*W float2 ~ 50 MB

    const int planes = in_sizes[0] / (IMG * IMG);  // 24

    dim3 grid(IMG / TX, IMG / TY, planes);
    guided_stage_a<<<grid, 256, 0, stream>>>(x, y, ab);
    guided_stage_b<<<grid, 256, 0, stream>>>(ab, x, out);
}